// Round 1
// baseline (81.181 us; speedup 1.0000x reference)
//
#include <hip/hip_runtime.h>

constexpr int NQ   = 10;
constexpr int QDIM = 1 << NQ;   // 1024 amplitudes
constexpr int CDIM = 768;
constexpr int NL   = 3;
constexpr int WPB  = 4;         // waves (= samples) per block

__global__ __launch_bounds__(64 * WPB) void qembed(
    const float* __restrict__ z,    // (B, CDIM)
    const float* __restrict__ Win,  // (CDIM, NQ)
    const float* __restrict__ bin,  // (NQ)
    const float* __restrict__ wts,  // (NL, NQ, 3)
    const float* __restrict__ Wout, // (NQ, CDIM)
    const float* __restrict__ bout, // (CDIM)
    float* __restrict__ out)        // (B, CDIM)
{
    __shared__ float2 stateAll[WPB][QDIM];
    const int wave = threadIdx.x >> 6;
    const int lane = threadIdx.x & 63;
    const int samp = blockIdx.x * WPB + wave;
    float2* S = stateAll[wave];

    // ---- angles = z[samp] @ Win + bin (wave-parallel dot products) ----
    float ang[NQ];
    {
        float acc[NQ];
#pragma unroll
        for (int q = 0; q < NQ; ++q) acc[q] = 0.f;
#pragma unroll
        for (int j = 0; j < CDIM / 64; ++j) {
            const int k = lane + j * 64;
            const float zv = z[(size_t)samp * CDIM + k];
#pragma unroll
            for (int q = 0; q < NQ; ++q) acc[q] += zv * Win[k * NQ + q];
        }
#pragma unroll
        for (int q = 0; q < NQ; ++q) {
            float v = acc[q];
#pragma unroll
            for (int off = 32; off >= 1; off >>= 1) v += __shfl_xor(v, off);
            ang[q] = v + bin[q];
        }
    }

    // ---- init |00...0> ----
#pragma unroll
    for (int j = 0; j < QDIM / 64; ++j) {
        const int i = lane + j * 64;
        S[i] = make_float2(i == 0 ? 1.f : 0.f, 0.f);
    }
    __syncthreads();

    // generic 1-qubit gate on index-bit b (wire w -> b = 9 - w)
    auto apply_gate = [&](int b, float2 g00, float2 g01, float2 g10, float2 g11) {
#pragma unroll
        for (int k = 0; k < (QDIM / 2) / 64; ++k) {
            const int p  = lane + k * 64;
            const int i0 = ((p >> b) << (b + 1)) | (p & ((1 << b) - 1));
            const int i1 = i0 | (1 << b);
            const float2 a0 = S[i0];
            const float2 a1 = S[i1];
            float2 n0, n1;
            n0.x = g00.x * a0.x - g00.y * a0.y + g01.x * a1.x - g01.y * a1.y;
            n0.y = g00.x * a0.y + g00.y * a0.x + g01.x * a1.y + g01.y * a1.x;
            n1.x = g10.x * a0.x - g10.y * a0.y + g11.x * a1.x - g11.y * a1.y;
            n1.y = g10.x * a0.y + g10.y * a0.x + g11.x * a1.y + g11.y * a1.x;
            S[i0] = n0;
            S[i1] = n1;
        }
        __syncthreads();
    };

    // ---- AngleEmbedding: RX(ang[q]) on wire q ----
    // RX(a) = [[cos(a/2), -i sin(a/2)], [-i sin(a/2), cos(a/2)]]
#pragma unroll
    for (int q = 0; q < NQ; ++q) {
        float sh, ch;
        sincosf(0.5f * ang[q], &sh, &ch);
        apply_gate(9 - q, make_float2(ch, 0.f), make_float2(0.f, -sh),
                          make_float2(0.f, -sh), make_float2(ch, 0.f));
    }

    // ---- StronglyEntanglingLayers ----
    for (int l = 0; l < NL; ++l) {
        for (int q = 0; q < NQ; ++q) {
            const float phi = wts[(l * NQ + q) * 3 + 0];
            const float th  = wts[(l * NQ + q) * 3 + 1];
            const float om  = wts[(l * NQ + q) * 3 + 2];
            float st, ct, sA, cA, sB, cB;
            sincosf(0.5f * th, &st, &ct);
            sincosf(0.5f * (phi + om), &sA, &cA);
            sincosf(0.5f * (phi - om), &sB, &cB);
            // Rot = RZ(om) RY(th) RZ(phi)
            const float2 g00 = make_float2( ct * cA, -ct * sA);
            const float2 g01 = make_float2(-st * cB, -st * sB);
            const float2 g10 = make_float2( st * cB, -st * sB);
            const float2 g11 = make_float2( ct * cA,  ct * sA);
            apply_gate(9 - q, g00, g01, g10, g11);
        }
        const int r = (l % (NQ - 1)) + 1;   // 1, 2, 3
        for (int i = 0; i < NQ; ++i) {
            const int bc = 9 - i;                    // control bit
            const int bt = 9 - ((i + r) % NQ);       // target bit
            const int b1 = bc < bt ? bc : bt;
            const int b2 = bc < bt ? bt : bc;
#pragma unroll
            for (int k = 0; k < (QDIM / 4) / 64; ++k) {
                const int p = lane + k * 64;
                int x = ((p >> b1) << (b1 + 1)) | (p & ((1 << b1) - 1));
                x     = ((x >> b2) << (b2 + 1)) | (x & ((1 << b2) - 1));
                const int i0 = x | (1 << bc);        // control=1, target=0
                const int i1 = i0 | (1 << bt);       // control=1, target=1
                const float2 t0 = S[i0];
                const float2 t1 = S[i1];
                S[i0] = t1;
                S[i1] = t0;
            }
            __syncthreads();
        }
    }

    // ---- expectation values <Z_w> ----
    float ev[NQ];
    {
        float acc[NQ];
#pragma unroll
        for (int q = 0; q < NQ; ++q) acc[q] = 0.f;
#pragma unroll
        for (int j = 0; j < QDIM / 64; ++j) {
            const int idx = lane + j * 64;
            const float2 a = S[idx];
            const float pr = a.x * a.x + a.y * a.y;
#pragma unroll
            for (int q = 0; q < NQ; ++q)
                acc[q] += ((idx >> (9 - q)) & 1) ? -pr : pr;
        }
#pragma unroll
        for (int q = 0; q < NQ; ++q) {
            float v = acc[q];
#pragma unroll
            for (int off = 32; off >= 1; off >>= 1) v += __shfl_xor(v, off);
            ev[q] = v;
        }
    }

    // ---- out[samp] = ev @ Wout + bout ----
#pragma unroll
    for (int j = 0; j < CDIM / 64; ++j) {
        const int d = lane + j * 64;
        float o = bout[d];
#pragma unroll
        for (int q = 0; q < NQ; ++q) o += ev[q] * Wout[q * CDIM + d];
        out[(size_t)samp * CDIM + d] = o;
    }
}

extern "C" void kernel_launch(void* const* d_in, const int* in_sizes, int n_in,
                              void* d_out, int out_size, void* d_ws, size_t ws_size,
                              hipStream_t stream) {
    const float* z    = (const float*)d_in[0];
    const float* Win  = (const float*)d_in[1];
    const float* bin  = (const float*)d_in[2];
    const float* wts  = (const float*)d_in[3];
    const float* Wout = (const float*)d_in[4];
    const float* bout = (const float*)d_in[5];
    float* outp       = (float*)d_out;

    const int batch  = in_sizes[0] / CDIM;   // 2048
    const int blocks = batch / WPB;          // 512
    qembed<<<blocks, 64 * WPB, 0, stream>>>(z, Win, bin, wts, Wout, bout, outp);
}

// Round 2
// 52.228 us; speedup vs baseline: 1.5543x; 1.5543x over previous
//
#include <hip/hip_runtime.h>

constexpr int NQ   = 10;
constexpr int CDIM = 768;
constexpr int NL   = 3;
constexpr int NREG = 16;   // index bits 6..9 live in the register index
constexpr int WPB  = 4;    // waves (= samples) per block

struct Gate { float2 g00, g01, g10, g11; };

__device__ __forceinline__ float shflx(float v, int mask) {
    return __shfl_xor(v, mask, 64);
}

// 1-qubit gate on index-bit B (wire w -> B = 9 - w)
template<int B>
__device__ __forceinline__ void gate_bit(float2 (&v)[NREG], int lane, Gate g) {
    if constexpr (B >= 6) {
        constexpr int rb = B - 6;
#pragma unroll
        for (int p = 0; p < NREG / 2; ++p) {
            const int r0 = ((p >> rb) << (rb + 1)) | (p & ((1 << rb) - 1));
            const int r1 = r0 | (1 << rb);
            const float2 a0 = v[r0], a1 = v[r1];
            v[r0].x = g.g00.x*a0.x - g.g00.y*a0.y + g.g01.x*a1.x - g.g01.y*a1.y;
            v[r0].y = g.g00.x*a0.y + g.g00.y*a0.x + g.g01.x*a1.y + g.g01.y*a1.x;
            v[r1].x = g.g10.x*a0.x - g.g10.y*a0.y + g.g11.x*a1.x - g.g11.y*a1.y;
            v[r1].y = g.g10.x*a0.y + g.g10.y*a0.x + g.g11.x*a1.y + g.g11.y*a1.x;
        }
    } else {
        const bool hi = (lane >> B) & 1;
        const float2 cO = hi ? g.g11 : g.g00;   // coeff on own amp
        const float2 cP = hi ? g.g10 : g.g01;   // coeff on partner amp
#pragma unroll
        for (int r = 0; r < NREG; ++r) {
            const float px = shflx(v[r].x, 1 << B);
            const float py = shflx(v[r].y, 1 << B);
            const float ox = v[r].x, oy = v[r].y;
            v[r].x = cO.x*ox - cO.y*oy + cP.x*px - cP.y*py;
            v[r].y = cO.x*oy + cO.y*ox + cP.x*py + cP.y*px;
        }
    }
}

// CNOT: swap amplitudes with control-bit=1 across target bit
template<int BC, int BT>
__device__ __forceinline__ void cnot(float2 (&v)[NREG], int lane) {
    if constexpr (BC >= 6 && BT >= 6) {          // both in registers: rename
        constexpr int rc = BC - 6, rt = BT - 6;
#pragma unroll
        for (int r = 0; r < NREG; ++r) {
            if (((r >> rc) & 1) && !((r >> rt) & 1)) {
                const int r1 = r | (1 << rt);
                const float2 t = v[r]; v[r] = v[r1]; v[r1] = t;
            }
        }
    } else if constexpr (BC >= 6) {              // control reg, target lane
        constexpr int rc = BC - 6;
#pragma unroll
        for (int r = 0; r < NREG; ++r) {
            if ((r >> rc) & 1) {
                v[r].x = shflx(v[r].x, 1 << BT);
                v[r].y = shflx(v[r].y, 1 << BT);
            }
        }
    } else if constexpr (BT >= 6) {              // control lane, target reg
        constexpr int rt = BT - 6;
        const bool c = (lane >> BC) & 1;
#pragma unroll
        for (int p = 0; p < NREG / 2; ++p) {
            const int r0 = ((p >> rt) << (rt + 1)) | (p & ((1 << rt) - 1));
            const int r1 = r0 | (1 << rt);
            const float2 a = v[r0], b = v[r1];
            v[r0] = c ? b : a;
            v[r1] = c ? a : b;
        }
    } else {                                     // both in lanes
        const bool c = (lane >> BC) & 1;
#pragma unroll
        for (int r = 0; r < NREG; ++r) {
            const float px = shflx(v[r].x, 1 << BT);
            const float py = shflx(v[r].y, 1 << BT);
            v[r].x = c ? px : v[r].x;
            v[r].y = c ? py : v[r].y;
        }
    }
}

template<int Q = 0>
__device__ __forceinline__ void rx_all(float2 (&v)[NREG], int lane, const float (&ang)[NQ]) {
    if constexpr (Q < NQ) {
        float s, c;
        __sincosf(0.5f * ang[Q], &s, &c);
        Gate g{{c, 0.f}, {0.f, -s}, {0.f, -s}, {c, 0.f}};
        gate_bit<9 - Q>(v, lane, g);
        rx_all<Q + 1>(v, lane, ang);
    }
}

template<int L, int Q = 0>
__device__ __forceinline__ void rot_layer(float2 (&v)[NREG], int lane, const float* __restrict__ wts) {
    if constexpr (Q < NQ) {
        const float phi = wts[(L * NQ + Q) * 3 + 0];
        const float th  = wts[(L * NQ + Q) * 3 + 1];
        const float om  = wts[(L * NQ + Q) * 3 + 2];
        float st, ct, sA, cA, sB, cB;
        __sincosf(0.5f * th, &st, &ct);
        __sincosf(0.5f * (phi + om), &sA, &cA);
        __sincosf(0.5f * (phi - om), &sB, &cB);
        // Rot = RZ(om) RY(th) RZ(phi)
        Gate g{{ ct * cA, -ct * sA},
               {-st * cB, -st * sB},
               { st * cB, -st * sB},
               { ct * cA,  ct * sA}};
        gate_bit<9 - Q>(v, lane, g);
        rot_layer<L, Q + 1>(v, lane, wts);
    }
}

template<int L, int I = 0>
__device__ __forceinline__ void cnot_ring(float2 (&v)[NREG], int lane) {
    if constexpr (I < NQ) {
        constexpr int R = (L % (NQ - 1)) + 1;
        cnot<9 - I, 9 - ((I + R) % NQ)>(v, lane);
        cnot_ring<L, I + 1>(v, lane);
    }
}

__global__ __launch_bounds__(64 * WPB) void qembed(
    const float* __restrict__ z,    // (B, CDIM)
    const float* __restrict__ Win,  // (CDIM, NQ)
    const float* __restrict__ bin,  // (NQ)
    const float* __restrict__ wts,  // (NL, NQ, 3)
    const float* __restrict__ Wout, // (NQ, CDIM)
    const float* __restrict__ bout, // (CDIM)
    float* __restrict__ out)        // (B, CDIM)
{
    const int wave = threadIdx.x >> 6;
    const int lane = threadIdx.x & 63;
    const int samp = blockIdx.x * WPB + wave;

    // ---- angles = z[samp] @ Win + bin (wave-parallel dot) ----
    float ang[NQ];
    {
        float acc[NQ];
#pragma unroll
        for (int q = 0; q < NQ; ++q) acc[q] = 0.f;
#pragma unroll
        for (int j = 0; j < CDIM / 64; ++j) {
            const int k = lane + j * 64;
            const float zv = z[(size_t)samp * CDIM + k];
#pragma unroll
            for (int q = 0; q < NQ; ++q) acc[q] += zv * Win[k * NQ + q];
        }
#pragma unroll
        for (int q = 0; q < NQ; ++q) {
            float s = acc[q];
#pragma unroll
            for (int off = 32; off >= 1; off >>= 1) s += shflx(s, off);
            ang[q] = s + bin[q];
        }
    }

    // ---- statevector in registers: v[r] = amp[(r<<6) | lane] ----
    float2 v[NREG];
#pragma unroll
    for (int r = 0; r < NREG; ++r) v[r] = make_float2(0.f, 0.f);
    if (lane == 0) v[0].x = 1.f;
    // make v live even for lane!=0 (avoid divergence weirdness): nothing needed

    rx_all(v, lane, ang);

    rot_layer<0>(v, lane, wts);  cnot_ring<0>(v, lane);
    rot_layer<1>(v, lane, wts);  cnot_ring<1>(v, lane);
    rot_layer<2>(v, lane, wts);  cnot_ring<2>(v, lane);

    // ---- expectation values <Z_w>, wire w <-> bit 9-w ----
    float pr[NREG];
#pragma unroll
    for (int r = 0; r < NREG; ++r) pr[r] = v[r].x * v[r].x + v[r].y * v[r].y;

    float sumAll = 0.f;
#pragma unroll
    for (int r = 0; r < NREG; ++r) sumAll += pr[r];

    float sgn[4];  // signed sums over register bits 0..3 (index bits 6..9)
#pragma unroll
    for (int rb = 0; rb < 4; ++rb) {
        float s = 0.f;
#pragma unroll
        for (int r = 0; r < NREG; ++r) s += ((r >> rb) & 1) ? -pr[r] : pr[r];
        sgn[rb] = s;
    }

    float ev[NQ];
#pragma unroll
    for (int w = 0; w < NQ; ++w) {
        const int b = 9 - w;
        float val = (b >= 6) ? sgn[b - 6]
                             : (((lane >> b) & 1) ? -sumAll : sumAll);
#pragma unroll
        for (int off = 32; off >= 1; off >>= 1) val += shflx(val, off);
        ev[w] = val;
    }

    // ---- out[samp] = ev @ Wout + bout ----
#pragma unroll
    for (int j = 0; j < CDIM / 64; ++j) {
        const int d = lane + j * 64;
        float o = bout[d];
#pragma unroll
        for (int q = 0; q < NQ; ++q) o += ev[q] * Wout[q * CDIM + d];
        out[(size_t)samp * CDIM + d] = o;
    }
}

extern "C" void kernel_launch(void* const* d_in, const int* in_sizes, int n_in,
                              void* d_out, int out_size, void* d_ws, size_t ws_size,
                              hipStream_t stream) {
    const float* z    = (const float*)d_in[0];
    const float* Win  = (const float*)d_in[1];
    const float* bin  = (const float*)d_in[2];
    const float* wts  = (const float*)d_in[3];
    const float* Wout = (const float*)d_in[4];
    const float* bout = (const float*)d_in[5];
    float* outp       = (float*)d_out;

    const int batch  = in_sizes[0] / CDIM;   // 2048
    const int blocks = batch / WPB;          // 512
    qembed<<<blocks, 64 * WPB, 0, stream>>>(z, Win, bin, wts, Wout, bout, outp);
}

// Round 4
// 41.563 us; speedup vs baseline: 1.9532x; 1.2566x over previous
//
#include <hip/hip_runtime.h>

constexpr int NQ   = 10;
constexpr int CDIM = 768;
constexpr int NL   = 3;
constexpr int NREG = 16;   // index bits 6..9 in the register index
constexpr int WPB  = 4;    // waves (= samples) per block

struct Gate { float2 g00, g01, g10, g11; };

template<int CTRL>
__device__ __forceinline__ float dppmov(float x) {
    return __int_as_float(__builtin_amdgcn_update_dpp(
        __float_as_int(x), __float_as_int(x), CTRL, 0xF, 0xF, true));
}

// y[l] = x[l ^ MASK], VALU-only for masks 1,2,4,8
template<int MASK>
__device__ __forceinline__ float lxor(float x, int lane) {
    if constexpr (MASK == 1)      return dppmov<0xB1>(x);   // quad_perm [1,0,3,2]
    else if constexpr (MASK == 2) return dppmov<0x4E>(x);   // quad_perm [2,3,0,1]
    else if constexpr (MASK == 4) {
        // row_shl:4 (0x104) -> src[i+4]; row_shr:4 (0x114) -> src[i-4]
        const float a = dppmov<0x104>(x);   // for lanes with bit2 = 0
        const float b = dppmov<0x114>(x);   // for lanes with bit2 = 1
        return ((lane >> 2) & 1) ? b : a;
    }
    else if constexpr (MASK == 8) return dppmov<0x128>(x);  // row_ror:8 == xor8
    else                          return __shfl_xor(x, MASK, 64);
}

__device__ __forceinline__ float wave_sum(float v, int lane) {
    v += lxor<1>(v, lane);
    v += lxor<2>(v, lane);
    v += lxor<4>(v, lane);
    v += lxor<8>(v, lane);
    v += __shfl_xor(v, 16, 64);
    v += __shfl_xor(v, 32, 64);
    return v;
}

// 1-qubit gate on index-bit B (wire w -> B = 9 - w)
template<int B>
__device__ __forceinline__ void gate_bit(float2 (&v)[NREG], int lane, Gate g) {
    if constexpr (B >= 6) {
        constexpr int rb = B - 6;
#pragma unroll
        for (int p = 0; p < NREG / 2; ++p) {
            const int r0 = ((p >> rb) << (rb + 1)) | (p & ((1 << rb) - 1));
            const int r1 = r0 | (1 << rb);
            const float2 a0 = v[r0], a1 = v[r1];
            v[r0].x = g.g00.x*a0.x - g.g00.y*a0.y + g.g01.x*a1.x - g.g01.y*a1.y;
            v[r0].y = g.g00.x*a0.y + g.g00.y*a0.x + g.g01.x*a1.y + g.g01.y*a1.x;
            v[r1].x = g.g10.x*a0.x - g.g10.y*a0.y + g.g11.x*a1.x - g.g11.y*a1.y;
            v[r1].y = g.g10.x*a0.y + g.g10.y*a0.x + g.g11.x*a1.y + g.g11.y*a1.x;
        }
    } else {
        const bool hi = (lane >> B) & 1;
        const float2 cO = hi ? g.g11 : g.g00;
        const float2 cP = hi ? g.g10 : g.g01;
#pragma unroll
        for (int r = 0; r < NREG; ++r) {
            const float px = lxor<1 << B>(v[r].x, lane);
            const float py = lxor<1 << B>(v[r].y, lane);
            const float ox = v[r].x, oy = v[r].y;
            v[r].x = cO.x*ox - cO.y*oy + cP.x*px - cP.y*py;
            v[r].y = cO.x*oy + cO.y*ox + cP.x*py + cP.y*px;
        }
    }
}

// CNOT: swap amplitudes with control-bit=1 across target bit
template<int BC, int BT>
__device__ __forceinline__ void cnot(float2 (&v)[NREG], int lane) {
    if constexpr (BC >= 6 && BT >= 6) {          // both reg: pure rename
        constexpr int rc = BC - 6, rt = BT - 6;
#pragma unroll
        for (int r = 0; r < NREG; ++r) {
            if (((r >> rc) & 1) && !((r >> rt) & 1)) {
                const int r1 = r | (1 << rt);
                const float2 t = v[r]; v[r] = v[r1]; v[r1] = t;
            }
        }
    } else if constexpr (BC >= 6) {              // control reg, target lane
        constexpr int rc = BC - 6;
#pragma unroll
        for (int r = 0; r < NREG; ++r) {
            if ((r >> rc) & 1) {
                v[r].x = lxor<1 << BT>(v[r].x, lane);
                v[r].y = lxor<1 << BT>(v[r].y, lane);
            }
        }
    } else if constexpr (BT >= 6) {              // control lane, target reg
        constexpr int rt = BT - 6;
        const bool c = (lane >> BC) & 1;
#pragma unroll
        for (int p = 0; p < NREG / 2; ++p) {
            const int r0 = ((p >> rt) << (rt + 1)) | (p & ((1 << rt) - 1));
            const int r1 = r0 | (1 << rt);
            const float2 a = v[r0], b = v[r1];
            v[r0] = c ? b : a;
            v[r1] = c ? a : b;
        }
    } else {                                     // both lane
        const bool c = (lane >> BC) & 1;
#pragma unroll
        for (int r = 0; r < NREG; ++r) {
            const float px = lxor<1 << BT>(v[r].x, lane);
            const float py = lxor<1 << BT>(v[r].y, lane);
            v[r].x = c ? px : v[r].x;
            v[r].y = c ? py : v[r].y;
        }
    }
}

// layer 0: fused F = Rot(l0,q) * RX(ang[q]) (RX applied first)
template<int Q = 0>
__device__ __forceinline__ void rxrot_layer0(float2 (&v)[NREG], int lane,
                                             const float (&ang)[NQ],
                                             const float* __restrict__ gates) {
    if constexpr (Q < NQ) {
        const float4* g4 = (const float4*)gates;
        const float4 p0 = g4[Q * 2];       // A=g00 (x,y), B=g01 (z,w)
        const float4 p1 = g4[Q * 2 + 1];   // C=g10 (x,y), D=g11 (z,w)
        float s, c;
        __sincosf(0.5f * ang[Q], &s, &c);
        Gate f;
        f.g00 = make_float2(p0.x*c + s*p0.w,  p0.y*c - s*p0.z);
        f.g01 = make_float2(s*p0.y + c*p0.z, -s*p0.x + c*p0.w);
        f.g10 = make_float2(p1.x*c + s*p1.w,  p1.y*c - s*p1.z);
        f.g11 = make_float2(s*p1.y + c*p1.z, -s*p1.x + c*p1.w);
        gate_bit<9 - Q>(v, lane, f);
        rxrot_layer0<Q + 1>(v, lane, ang, gates);
    }
}

template<int L, int Q = 0>
__device__ __forceinline__ void rot_layer(float2 (&v)[NREG], int lane,
                                          const float* __restrict__ gates) {
    if constexpr (Q < NQ) {
        const float4* g4 = (const float4*)gates;
        const float4 p0 = g4[(L * NQ + Q) * 2];
        const float4 p1 = g4[(L * NQ + Q) * 2 + 1];
        Gate g{{p0.x, p0.y}, {p0.z, p0.w}, {p1.x, p1.y}, {p1.z, p1.w}};
        gate_bit<9 - Q>(v, lane, g);
        rot_layer<L, Q + 1>(v, lane, gates);
    }
}

template<int L, int I = 0>
__device__ __forceinline__ void cnot_ring(float2 (&v)[NREG], int lane) {
    if constexpr (I < NQ) {
        constexpr int R = (L % (NQ - 1)) + 1;
        cnot<9 - I, 9 - ((I + R) % NQ)>(v, lane);
        cnot_ring<L, I + 1>(v, lane);
    }
}

// precompute the 30 wave-uniform Rot matrices once
__global__ void prep_gates(const float* __restrict__ wts, float* __restrict__ gates) {
    const int t = threadIdx.x;
    if (t < NL * NQ) {
        const float phi = wts[t * 3 + 0];
        const float th  = wts[t * 3 + 1];
        const float om  = wts[t * 3 + 2];
        float st, ct, sA, cA, sB, cB;
        sincosf(0.5f * th, &st, &ct);
        sincosf(0.5f * (phi + om), &sA, &cA);
        sincosf(0.5f * (phi - om), &sB, &cB);
        float* g = gates + t * 8;
        g[0] =  ct * cA; g[1] = -ct * sA;   // g00
        g[2] = -st * cB; g[3] = -st * sB;   // g01
        g[4] =  st * cB; g[5] = -st * sB;   // g10
        g[6] =  ct * cA; g[7] =  ct * sA;   // g11
    }
}

__global__ __launch_bounds__(64 * WPB) void qembed(
    const float* __restrict__ z,     // (B, CDIM)
    const float* __restrict__ Win,   // (CDIM, NQ)
    const float* __restrict__ bin,   // (NQ)
    const float* __restrict__ gates, // (NL*NQ, 8) precomputed
    const float* __restrict__ Wout,  // (NQ, CDIM)
    const float* __restrict__ bout,  // (CDIM)
    float* __restrict__ out)         // (B, CDIM)
{
    const int wave = threadIdx.x >> 6;
    const int lane = threadIdx.x & 63;
    const int samp = blockIdx.x * WPB + wave;

    // ---- angles = z[samp] @ Win + bin ----
    float ang[NQ];
    {
        float acc[NQ];
#pragma unroll
        for (int q = 0; q < NQ; ++q) acc[q] = 0.f;
#pragma unroll
        for (int j = 0; j < CDIM / 64; ++j) {
            const int k = lane + j * 64;
            const float zv = z[(size_t)samp * CDIM + k];
#pragma unroll
            for (int q = 0; q < NQ; ++q) acc[q] += zv * Win[k * NQ + q];
        }
#pragma unroll
        for (int q = 0; q < NQ; ++q) ang[q] = wave_sum(acc[q], lane) + bin[q];
    }

    // ---- statevector in registers: v[r] = amp[(r<<6) | lane] ----
    float2 v[NREG];
#pragma unroll
    for (int r = 0; r < NREG; ++r) v[r] = make_float2(0.f, 0.f);
    if (lane == 0) v[0].x = 1.f;

    rxrot_layer0(v, lane, ang, gates);  cnot_ring<0>(v, lane);
    rot_layer<1>(v, lane, gates);       cnot_ring<1>(v, lane);
    rot_layer<2>(v, lane, gates);       cnot_ring<2>(v, lane);

    // ---- expectation values <Z_w>, wire w <-> bit 9-w ----
    float pr[NREG];
#pragma unroll
    for (int r = 0; r < NREG; ++r) pr[r] = v[r].x * v[r].x + v[r].y * v[r].y;

    float sumAll = 0.f;
#pragma unroll
    for (int r = 0; r < NREG; ++r) sumAll += pr[r];

    float sgn[4];
#pragma unroll
    for (int rb = 0; rb < 4; ++rb) {
        float s = 0.f;
#pragma unroll
        for (int r = 0; r < NREG; ++r) s += ((r >> rb) & 1) ? -pr[r] : pr[r];
        sgn[rb] = s;
    }

    float ev[NQ];
#pragma unroll
    for (int w = 0; w < NQ; ++w) {
        const int b = 9 - w;
        const float val = (b >= 6) ? sgn[b - 6]
                                   : (((lane >> b) & 1) ? -sumAll : sumAll);
        ev[w] = wave_sum(val, lane);
    }

    // ---- out[samp] = ev @ Wout + bout ----
#pragma unroll
    for (int j = 0; j < CDIM / 64; ++j) {
        const int d = lane + j * 64;
        float o = bout[d];
#pragma unroll
        for (int q = 0; q < NQ; ++q) o += ev[q] * Wout[q * CDIM + d];
        out[(size_t)samp * CDIM + d] = o;
    }
}

extern "C" void kernel_launch(void* const* d_in, const int* in_sizes, int n_in,
                              void* d_out, int out_size, void* d_ws, size_t ws_size,
                              hipStream_t stream) {
    const float* z    = (const float*)d_in[0];
    const float* Win  = (const float*)d_in[1];
    const float* bin  = (const float*)d_in[2];
    const float* wts  = (const float*)d_in[3];
    const float* Wout = (const float*)d_in[4];
    const float* bout = (const float*)d_in[5];
    float* outp       = (float*)d_out;
    float* gates      = (float*)d_ws;       // 30 gates * 8 floats = 960 B

    prep_gates<<<1, 64, 0, stream>>>(wts, gates);

    const int batch  = in_sizes[0] / CDIM;   // 2048
    const int blocks = batch / WPB;          // 512
    qembed<<<blocks, 64 * WPB, 0, stream>>>(z, Win, bin, gates, Wout, bout, outp);
}

// Round 5
// 40.210 us; speedup vs baseline: 2.0189x; 1.0337x over previous
//
#include <hip/hip_runtime.h>

typedef float f2 __attribute__((ext_vector_type(2)));   // complex (re, im)

constexpr int NQ   = 10;
constexpr int CDIM = 768;
constexpr int NL   = 3;
constexpr int NREG = 16;   // index bits 6..9 in the register index
constexpr int WPB  = 4;    // waves (= samples) per block

// ---------- cross-lane primitives (all VALU, no LDS pipe) ----------

template<int CTRL>
__device__ __forceinline__ float dppmov(float x) {
    return __int_as_float(__builtin_amdgcn_update_dpp(
        __float_as_int(x), __float_as_int(x), CTRL, 0xF, 0xF, true));
}

// y[l] = x[l ^ MASK] for MASK in {1,2,4,8}
template<int MASK>
__device__ __forceinline__ float lxor(float x, int lane) {
    static_assert(MASK == 1 || MASK == 2 || MASK == 4 || MASK == 8, "");
    if constexpr (MASK == 1)      return dppmov<0xB1>(x);   // quad_perm [1,0,3,2]
    else if constexpr (MASK == 2) return dppmov<0x4E>(x);   // quad_perm [2,3,0,1]
    else if constexpr (MASK == 4) {
        const float a = dppmov<0x104>(x);   // row_shl:4 -> src[i+4] (bit2=0 lanes)
        const float b = dppmov<0x114>(x);   // row_shr:4 -> src[i-4] (bit2=1 lanes)
        return ((lane >> 2) & 1) ? b : a;
    }
    else                          return dppmov<0x128>(x);  // row_ror:8 == xor8
}

// B in {4,5}: lo = x[l & ~(1<<B)], hi = x[l | (1<<B)]  (one swap instr)
template<int B>
__device__ __forceinline__ void swap2(float x, float& lo, float& hi) {
    const unsigned xu = __float_as_uint(x);
#if __has_builtin(__builtin_amdgcn_permlane16_swap) && __has_builtin(__builtin_amdgcn_permlane32_swap)
    if constexpr (B == 4) {
        auto r = __builtin_amdgcn_permlane16_swap(xu, xu, false, false);
        lo = __uint_as_float(r[0]); hi = __uint_as_float(r[1]);
    } else {
        auto r = __builtin_amdgcn_permlane32_swap(xu, xu, false, false);
        lo = __uint_as_float(r[0]); hi = __uint_as_float(r[1]);
    }
#else
    float d, s;
    if constexpr (B == 4)
        asm("v_mov_b32 %0, %2\n\tv_mov_b32 %1, %2\n\ts_nop 1\n\t"
            "v_permlane16_swap_b32 %0, %1"
            : "=&v"(d), "=&v"(s) : "v"(x));
    else
        asm("v_mov_b32 %0, %2\n\tv_mov_b32 %1, %2\n\ts_nop 1\n\t"
            "v_permlane32_swap_b32 %0, %1"
            : "=&v"(d), "=&v"(s) : "v"(x));
    lo = d; hi = s;
#endif
}

__device__ __forceinline__ float wave_sum(float v) {
    v += dppmov<0xB1>(v);    // xor1
    v += dppmov<0x4E>(v);    // xor2
    v += dppmov<0x141>(v);   // row_half_mirror = xor7 (bits 0-1 already uniform)
    v += dppmov<0x140>(v);   // row_mirror = xor15 (bits 0-2 uniform)
    float lo, hi;
    swap2<4>(v, lo, hi); v = lo + hi;
    swap2<5>(v, lo, hi); v = lo + hi;
    return v;
}

// ---------- complex helpers (packed-math friendly) ----------

__device__ __forceinline__ f2 swapneg(f2 b) { f2 r; r.x = -b.y; r.y = b.x; return r; }
__device__ __forceinline__ f2 cmul(f2 a, f2 b) { return b * a.x + swapneg(b) * a.y; }
__device__ __forceinline__ f2 cfma(f2 a, f2 b, f2 acc) { return acc + b * a.x + swapneg(b) * a.y; }

// ---------- 1-qubit gate on index-bit B (wire w -> B = 9 - w) ----------

template<int B>
__device__ __forceinline__ void gate_bit(f2 (&v)[NREG], int lane,
                                         f2 g00, f2 g01, f2 g10, f2 g11) {
    if constexpr (B >= 6) {                       // register bit: pure in-reg
        constexpr int rb = B - 6;
#pragma unroll
        for (int p = 0; p < NREG / 2; ++p) {
            const int r0 = ((p >> rb) << (rb + 1)) | (p & ((1 << rb) - 1));
            const int r1 = r0 | (1 << rb);
            const f2 a0 = v[r0], a1 = v[r1];
            v[r0] = cfma(g01, a1, cmul(g00, a0));
            v[r1] = cfma(g11, a1, cmul(g10, a0));
        }
    } else if constexpr (B >= 4) {                // lane bit via permlane swap
        const bool hb = (lane >> B) & 1;
        const f2 A  = hb ? g10 : g00;             // coeff on lo value
        const f2 Bc = hb ? g11 : g01;             // coeff on hi value
#pragma unroll
        for (int r = 0; r < NREG; ++r) {
            float lx, hx, ly, hy;
            swap2<B>(v[r].x, lx, hx);
            swap2<B>(v[r].y, ly, hy);
            f2 lo; lo.x = lx; lo.y = ly;
            f2 hi; hi.x = hx; hi.y = hy;
            v[r] = cfma(Bc, hi, cmul(A, lo));
        }
    } else {                                      // lane bit via DPP
        const bool hb = (lane >> B) & 1;
        const f2 cO = hb ? g11 : g00;
        const f2 cP = hb ? g10 : g01;
#pragma unroll
        for (int r = 0; r < NREG; ++r) {
            f2 p;
            p.x = lxor<(1 << B)>(v[r].x, lane);
            p.y = lxor<(1 << B)>(v[r].y, lane);
            v[r] = cfma(cP, p, cmul(cO, v[r]));
        }
    }
}

// partner value x[l ^ (1<<BT)] for lane-resident target bit
template<int BT>
__device__ __forceinline__ float partner(float x, int lane) {
    if constexpr (BT >= 4) {
        float lo, hi; swap2<BT>(x, lo, hi);
        return ((lane >> BT) & 1) ? lo : hi;
    } else return lxor<(1 << BT)>(x, lane);
}

// ---------- CNOT ----------

template<int BC, int BT>
__device__ __forceinline__ void cnot(f2 (&v)[NREG], int lane) {
    if constexpr (BC >= 6 && BT >= 6) {           // both reg: free rename
        constexpr int rc = BC - 6, rt = BT - 6;
#pragma unroll
        for (int r = 0; r < NREG; ++r)
            if (((r >> rc) & 1) && !((r >> rt) & 1)) {
                const int r1 = r | (1 << rt);
                const f2 t = v[r]; v[r] = v[r1]; v[r1] = t;
            }
    } else if constexpr (BC >= 6) {               // reg control, lane target
        constexpr int rc = BC - 6;
#pragma unroll
        for (int r = 0; r < NREG; ++r)
            if ((r >> rc) & 1) {
                const float px = partner<BT>(v[r].x, lane);
                const float py = partner<BT>(v[r].y, lane);
                f2 n; n.x = px; n.y = py; v[r] = n;
            }
    } else if constexpr (BT >= 6) {               // lane control, reg target
        constexpr int rt = BT - 6;
        const bool c = (lane >> BC) & 1;
#pragma unroll
        for (int p = 0; p < NREG / 2; ++p) {
            const int r0 = ((p >> rt) << (rt + 1)) | (p & ((1 << rt) - 1));
            const int r1 = r0 | (1 << rt);
            const f2 a = v[r0], b = v[r1];
            v[r0] = c ? b : a;
            v[r1] = c ? a : b;
        }
    } else {                                      // both lane
        const bool c = (lane >> BC) & 1;
#pragma unroll
        for (int r = 0; r < NREG; ++r) {
            const float px = partner<BT>(v[r].x, lane);
            const float py = partner<BT>(v[r].y, lane);
            f2 n;
            n.x = c ? px : v[r].x;
            n.y = c ? py : v[r].y;
            v[r] = n;
        }
    }
}

// ---------- layer drivers ----------

template<int L, int Q = 0>
__device__ __forceinline__ void rot_layer(f2 (&v)[NREG], int lane,
                                          const float* g /*LDS*/) {
    if constexpr (Q < NQ) {
        const float* p = g + (L * NQ + Q) * 8;
        f2 g00, g01, g10, g11;
        g00.x = p[0]; g00.y = p[1]; g01.x = p[2]; g01.y = p[3];
        g10.x = p[4]; g10.y = p[5]; g11.x = p[6]; g11.y = p[7];
        gate_bit<9 - Q>(v, lane, g00, g01, g10, g11);
        rot_layer<L, Q + 1>(v, lane, g);
    }
}

template<int L, int I = 0>
__device__ __forceinline__ void cnot_ring(f2 (&v)[NREG], int lane) {
    if constexpr (I < NQ) {
        constexpr int R = (L % (NQ - 1)) + 1;
        cnot<9 - I, 9 - ((I + R) % NQ)>(v, lane);
        cnot_ring<L, I + 1>(v, lane);
    }
}

// ---------- main kernel ----------

__global__ __launch_bounds__(64 * WPB) void qembed(
    const float* __restrict__ z,     // (B, CDIM)
    const float* __restrict__ Win,   // (CDIM, NQ)
    const float* __restrict__ bin,   // (NQ)
    const float* __restrict__ wts,   // (NL, NQ, 3)
    const float* __restrict__ Wout,  // (NQ, CDIM)
    const float* __restrict__ bout,  // (CDIM)
    float* __restrict__ out)         // (B, CDIM)
{
    __shared__ float gl[NL * NQ * 8];
    const int wave = threadIdx.x >> 6;
    const int lane = threadIdx.x & 63;
    const int samp = blockIdx.x * WPB + wave;

    // wave 0: the 30 wave-uniform Rot matrices -> LDS (replaces prep kernel)
    if (wave == 0 && lane < NL * NQ) {
        const float phi = wts[lane * 3 + 0];
        const float th  = wts[lane * 3 + 1];
        const float om  = wts[lane * 3 + 2];
        float st, ct, sA, cA, sB, cB;
        __sincosf(0.5f * th, &st, &ct);
        __sincosf(0.5f * (phi + om), &sA, &cA);
        __sincosf(0.5f * (phi - om), &sB, &cB);
        float* g = gl + lane * 8;
        g[0] =  ct * cA; g[1] = -ct * sA;   // g00
        g[2] = -st * cB; g[3] = -st * sB;   // g01
        g[4] =  st * cB; g[5] = -st * sB;   // g10
        g[6] =  ct * cA; g[7] =  ct * sA;   // g11
    }

    // ---- angles = z[samp] @ Win + bin ----
    float ang[NQ];
    {
        float acc[NQ];
#pragma unroll
        for (int q = 0; q < NQ; ++q) acc[q] = 0.f;
        const float* zrow = z + (size_t)samp * CDIM;
#pragma unroll
        for (int j = 0; j < CDIM / 64; ++j) {
            const int k = lane + j * 64;
            const float zv = zrow[k];
            const f2* wr = (const f2*)(Win + k * NQ);   // 8B-aligned (k*10 even)
#pragma unroll
            for (int h = 0; h < NQ / 2; ++h) {
                const f2 w = wr[h];
                acc[2 * h]     += zv * w.x;
                acc[2 * h + 1] += zv * w.y;
            }
        }
#pragma unroll
        for (int q = 0; q < NQ; ++q) ang[q] = wave_sum(acc[q]) + bin[q];
    }

    __syncthreads();   // gl ready

    // ---- layer 0 on |0..0>: product state built directly ----
    // fused F_q = Rot(l0,q) * RX(ang_q); only its first column (f0,f1) matters
    f2 f0[NQ], f1[NQ];
#pragma unroll
    for (int q = 0; q < NQ; ++q) {
        const float* g = gl + q * 8;
        float s, c;
        __sincosf(0.5f * ang[q], &s, &c);
        f2 a, b;
        a.x = g[0] * c + s * g[3];  a.y = g[1] * c - s * g[2];
        b.x = g[4] * c + s * g[7];  b.y = g[5] * c - s * g[6];
        f0[q] = a; f1[q] = b;
    }
    // lane-bit factors: bit b (0..5) <-> wire 9-b
    f2 s0 = ((lane >> 0) & 1) ? f1[9] : f0[9];
    f2 s1 = ((lane >> 1) & 1) ? f1[8] : f0[8];
    f2 s2 = ((lane >> 2) & 1) ? f1[7] : f0[7];
    f2 s3 = ((lane >> 3) & 1) ? f1[6] : f0[6];
    f2 s4 = ((lane >> 4) & 1) ? f1[5] : f0[5];
    f2 s5 = ((lane >> 5) & 1) ? f1[4] : f0[4];
    const f2 L = cmul(cmul(cmul(s0, s1), cmul(s2, s3)), cmul(s4, s5));

    f2 LT[4], U2[4];
#pragma unroll
    for (int j = 0; j < 4; ++j) {
        // reg bits 0,1 <-> index bits 6,7 <-> wires 3,2
        const f2 t = cmul((j & 1) ? f1[3] : f0[3], (j & 2) ? f1[2] : f0[2]);
        LT[j] = cmul(L, t);
        // reg bits 2,3 <-> index bits 8,9 <-> wires 1,0
        U2[j] = cmul((j & 1) ? f1[1] : f0[1], (j & 2) ? f1[0] : f0[0]);
    }
    f2 v[NREG];
#pragma unroll
    for (int r = 0; r < NREG; ++r) v[r] = cmul(LT[r & 3], U2[r >> 2]);

    // ---- remaining circuit ----
    cnot_ring<0>(v, lane);
    rot_layer<1>(v, lane, gl);  cnot_ring<1>(v, lane);
    rot_layer<2>(v, lane, gl);  cnot_ring<2>(v, lane);

    // ---- expectation values <Z_w>, wire w <-> bit 9-w ----
    float pr[NREG];
#pragma unroll
    for (int r = 0; r < NREG; ++r) pr[r] = v[r].x * v[r].x + v[r].y * v[r].y;

    float sumAll = 0.f;
#pragma unroll
    for (int r = 0; r < NREG; ++r) sumAll += pr[r];

    float sgn[4];
#pragma unroll
    for (int rb = 0; rb < 4; ++rb) {
        float s = 0.f;
#pragma unroll
        for (int r = 0; r < NREG; ++r) s += ((r >> rb) & 1) ? -pr[r] : pr[r];
        sgn[rb] = s;
    }

    float ev[NQ];
#pragma unroll
    for (int w = 0; w < NQ; ++w) {
        const int b = 9 - w;
        const float val = (b >= 6) ? sgn[b - 6]
                                   : (((lane >> b) & 1) ? -sumAll : sumAll);
        ev[w] = wave_sum(val);
    }

    // ---- out[samp] = ev @ Wout + bout ----
#pragma unroll
    for (int j = 0; j < CDIM / 64; ++j) {
        const int d = lane + j * 64;
        float o = bout[d];
#pragma unroll
        for (int q = 0; q < NQ; ++q) o += ev[q] * Wout[q * CDIM + d];
        out[(size_t)samp * CDIM + d] = o;
    }
}

extern "C" void kernel_launch(void* const* d_in, const int* in_sizes, int n_in,
                              void* d_out, int out_size, void* d_ws, size_t ws_size,
                              hipStream_t stream) {
    const float* z    = (const float*)d_in[0];
    const float* Win  = (const float*)d_in[1];
    const float* bin  = (const float*)d_in[2];
    const float* wts  = (const float*)d_in[3];
    const float* Wout = (const float*)d_in[4];
    const float* bout = (const float*)d_in[5];
    float* outp       = (float*)d_out;

    const int batch  = in_sizes[0] / CDIM;   // 2048
    const int blocks = batch / WPB;          // 512
    qembed<<<blocks, 64 * WPB, 0, stream>>>(z, Win, bin, wts, Wout, bout, outp);
}

// Round 6
// 34.425 us; speedup vs baseline: 2.3582x; 1.1680x over previous
//
#include <hip/hip_runtime.h>

typedef float f2 __attribute__((ext_vector_type(2)));   // complex (re, im)

constexpr int NQ   = 10;
constexpr int CDIM = 768;
constexpr int NL   = 3;
constexpr int NREG = 16;   // index bits 6..9 in the register index
constexpr int WPB  = 4;    // waves (= samples) per block

// ---------- cross-lane primitives (all VALU, no LDS pipe) ----------

template<int CTRL>
__device__ __forceinline__ float dppmov(float x) {
    return __int_as_float(__builtin_amdgcn_update_dpp(
        __float_as_int(x), __float_as_int(x), CTRL, 0xF, 0xF, true));
}

// y[l] = x[l ^ MASK] for MASK in {1,2,4,8}
template<int MASK>
__device__ __forceinline__ float lxor(float x, int lane) {
    static_assert(MASK == 1 || MASK == 2 || MASK == 4 || MASK == 8, "");
    if constexpr (MASK == 1)      return dppmov<0xB1>(x);   // quad_perm [1,0,3,2]
    else if constexpr (MASK == 2) return dppmov<0x4E>(x);   // quad_perm [2,3,0,1]
    else if constexpr (MASK == 4) {
        const float a = dppmov<0x104>(x);   // row_shl:4 -> src[i+4] (bit2=0 lanes)
        const float b = dppmov<0x114>(x);   // row_shr:4 -> src[i-4] (bit2=1 lanes)
        return ((lane >> 2) & 1) ? b : a;
    }
    else                          return dppmov<0x128>(x);  // row_ror:8 == xor8
}

// B in {4,5}: lo = x[l & ~(1<<B)], hi = x[l | (1<<B)]  (one swap instr)
template<int B>
__device__ __forceinline__ void swap2(float x, float& lo, float& hi) {
    const unsigned xu = __float_as_uint(x);
#if __has_builtin(__builtin_amdgcn_permlane16_swap) && __has_builtin(__builtin_amdgcn_permlane32_swap)
    if constexpr (B == 4) {
        auto r = __builtin_amdgcn_permlane16_swap(xu, xu, false, false);
        lo = __uint_as_float(r[0]); hi = __uint_as_float(r[1]);
    } else {
        auto r = __builtin_amdgcn_permlane32_swap(xu, xu, false, false);
        lo = __uint_as_float(r[0]); hi = __uint_as_float(r[1]);
    }
#else
    float d, s;
    if constexpr (B == 4)
        asm("v_mov_b32 %0, %2\n\tv_mov_b32 %1, %2\n\ts_nop 1\n\t"
            "v_permlane16_swap_b32 %0, %1"
            : "=&v"(d), "=&v"(s) : "v"(x));
    else
        asm("v_mov_b32 %0, %2\n\tv_mov_b32 %1, %2\n\ts_nop 1\n\t"
            "v_permlane32_swap_b32 %0, %1"
            : "=&v"(d), "=&v"(s) : "v"(x));
    lo = d; hi = s;
#endif
}

__device__ __forceinline__ float wave_sum(float v) {
    v += dppmov<0xB1>(v);    // xor1
    v += dppmov<0x4E>(v);    // xor2
    v += dppmov<0x141>(v);   // row_half_mirror = xor7 (bits 0-1 already uniform)
    v += dppmov<0x140>(v);   // row_mirror = xor15 (bits 0-2 uniform)
    float lo, hi;
    swap2<4>(v, lo, hi); v = lo + hi;
    swap2<5>(v, lo, hi); v = lo + hi;
    return v;
}

// ---------- complex helpers (packed-math friendly) ----------

__device__ __forceinline__ f2 swapneg(f2 b) { f2 r; r.x = -b.y; r.y = b.x; return r; }
__device__ __forceinline__ f2 cmul(f2 a, f2 b) { return b * a.x + swapneg(b) * a.y; }
__device__ __forceinline__ f2 cfma(f2 a, f2 b, f2 acc) { return acc + b * a.x + swapneg(b) * a.y; }

// ---------- 1-qubit gate on index-bit B (wire w -> B = 9 - w) ----------

template<int B>
__device__ __forceinline__ void gate_bit(f2 (&v)[NREG], int lane,
                                         f2 g00, f2 g01, f2 g10, f2 g11) {
    if constexpr (B >= 6) {                       // register bit: pure in-reg
        constexpr int rb = B - 6;
#pragma unroll
        for (int p = 0; p < NREG / 2; ++p) {
            const int r0 = ((p >> rb) << (rb + 1)) | (p & ((1 << rb) - 1));
            const int r1 = r0 | (1 << rb);
            const f2 a0 = v[r0], a1 = v[r1];
            v[r0] = cfma(g01, a1, cmul(g00, a0));
            v[r1] = cfma(g11, a1, cmul(g10, a0));
        }
    } else if constexpr (B >= 4) {                // lane bit via permlane swap
        const bool hb = (lane >> B) & 1;
        const f2 A  = hb ? g10 : g00;             // coeff on lo value
        const f2 Bc = hb ? g11 : g01;             // coeff on hi value
#pragma unroll
        for (int r = 0; r < NREG; ++r) {
            float lx, hx, ly, hy;
            swap2<B>(v[r].x, lx, hx);
            swap2<B>(v[r].y, ly, hy);
            f2 lo; lo.x = lx; lo.y = ly;
            f2 hi; hi.x = hx; hi.y = hy;
            v[r] = cfma(Bc, hi, cmul(A, lo));
        }
    } else {                                      // lane bit via DPP
        const bool hb = (lane >> B) & 1;
        const f2 cO = hb ? g11 : g00;
        const f2 cP = hb ? g10 : g01;
#pragma unroll
        for (int r = 0; r < NREG; ++r) {
            f2 p;
            p.x = lxor<(1 << B)>(v[r].x, lane);
            p.y = lxor<(1 << B)>(v[r].y, lane);
            v[r] = cfma(cP, p, cmul(cO, v[r]));
        }
    }
}

// partner value x[l ^ (1<<BT)] for lane-resident target bit
template<int BT>
__device__ __forceinline__ float partner(float x, int lane) {
    if constexpr (BT >= 4) {
        float lo, hi; swap2<BT>(x, lo, hi);
        return ((lane >> BT) & 1) ? lo : hi;
    } else return lxor<(1 << BT)>(x, lane);
}

// ---------- CNOT ----------

template<int BC, int BT>
__device__ __forceinline__ void cnot(f2 (&v)[NREG], int lane) {
    if constexpr (BC >= 6 && BT >= 6) {           // both reg: free rename
        constexpr int rc = BC - 6, rt = BT - 6;
#pragma unroll
        for (int r = 0; r < NREG; ++r)
            if (((r >> rc) & 1) && !((r >> rt) & 1)) {
                const int r1 = r | (1 << rt);
                const f2 t = v[r]; v[r] = v[r1]; v[r1] = t;
            }
    } else if constexpr (BC >= 6) {               // reg control, lane target
        constexpr int rc = BC - 6;
#pragma unroll
        for (int r = 0; r < NREG; ++r)
            if ((r >> rc) & 1) {
                const float px = partner<BT>(v[r].x, lane);
                const float py = partner<BT>(v[r].y, lane);
                f2 n; n.x = px; n.y = py; v[r] = n;
            }
    } else if constexpr (BT >= 6) {               // lane control, reg target
        constexpr int rt = BT - 6;
        const bool c = (lane >> BC) & 1;
#pragma unroll
        for (int p = 0; p < NREG / 2; ++p) {
            const int r0 = ((p >> rt) << (rt + 1)) | (p & ((1 << rt) - 1));
            const int r1 = r0 | (1 << rt);
            const f2 a = v[r0], b = v[r1];
            v[r0] = c ? b : a;
            v[r1] = c ? a : b;
        }
    } else {                                      // both lane
        const bool c = (lane >> BC) & 1;
#pragma unroll
        for (int r = 0; r < NREG; ++r) {
            const float px = partner<BT>(v[r].x, lane);
            const float py = partner<BT>(v[r].y, lane);
            f2 n;
            n.x = c ? px : v[r].x;
            n.y = c ? py : v[r].y;
            v[r] = n;
        }
    }
}

// ---------- layer drivers ----------

template<int L, int Q = 0>
__device__ __forceinline__ void rot_layer(f2 (&v)[NREG], int lane,
                                          const float* __restrict__ gates) {
    if constexpr (Q < NQ) {
        const float4* g4 = (const float4*)gates;       // uniform -> s_load
        const float4 p0 = g4[(L * NQ + Q) * 2];
        const float4 p1 = g4[(L * NQ + Q) * 2 + 1];
        f2 g00 = {p0.x, p0.y}, g01 = {p0.z, p0.w};
        f2 g10 = {p1.x, p1.y}, g11 = {p1.z, p1.w};
        gate_bit<9 - Q>(v, lane, g00, g01, g10, g11);
        rot_layer<L, Q + 1>(v, lane, gates);
    }
}

template<int L, int I = 0>
__device__ __forceinline__ void cnot_ring(f2 (&v)[NREG], int lane) {
    if constexpr (I < NQ) {
        constexpr int R = (L % (NQ - 1)) + 1;
        cnot<9 - I, 9 - ((I + R) % NQ)>(v, lane);
        cnot_ring<L, I + 1>(v, lane);
    }
}

// precompute the 30 wave-uniform Rot matrices once
__global__ void prep_gates(const float* __restrict__ wts, float* __restrict__ gates) {
    const int t = threadIdx.x;
    if (t < NL * NQ) {
        const float phi = wts[t * 3 + 0];
        const float th  = wts[t * 3 + 1];
        const float om  = wts[t * 3 + 2];
        float st, ct, sA, cA, sB, cB;
        sincosf(0.5f * th, &st, &ct);
        sincosf(0.5f * (phi + om), &sA, &cA);
        sincosf(0.5f * (phi - om), &sB, &cB);
        float* g = gates + t * 8;
        g[0] =  ct * cA; g[1] = -ct * sA;   // g00
        g[2] = -st * cB; g[3] = -st * sB;   // g01
        g[4] =  st * cB; g[5] = -st * sB;   // g10
        g[6] =  ct * cA; g[7] =  ct * sA;   // g11
    }
}

// ---------- main kernel ----------
// (256, 2): grid is capped at 2048 waves = 2/SIMD anyway -> allow 256 VGPRs
__global__ __launch_bounds__(64 * WPB, 2) void qembed(
    const float* __restrict__ z,     // (B, CDIM)
    const float* __restrict__ Win,   // (CDIM, NQ)
    const float* __restrict__ bin,   // (NQ)
    const float* __restrict__ gates, // (NL*NQ, 8) precomputed
    const float* __restrict__ Wout,  // (NQ, CDIM)
    const float* __restrict__ bout,  // (CDIM)
    float* __restrict__ out)         // (B, CDIM)
{
    const int wave = threadIdx.x >> 6;
    const int lane = threadIdx.x & 63;
    const int samp = blockIdx.x * WPB + wave;

    // ---- angles = z[samp] @ Win + bin ----
    float ang[NQ];
    {
        float acc[NQ];
#pragma unroll
        for (int q = 0; q < NQ; ++q) acc[q] = 0.f;
        const float* zrow = z + (size_t)samp * CDIM;
#pragma unroll
        for (int j = 0; j < CDIM / 64; ++j) {
            const int k = lane + j * 64;
            const float zv = zrow[k];
            const f2* wr = (const f2*)(Win + k * NQ);   // 8B-aligned (k*10 even)
#pragma unroll
            for (int h = 0; h < NQ / 2; ++h) {
                const f2 w = wr[h];
                acc[2 * h]     += zv * w.x;
                acc[2 * h + 1] += zv * w.y;
            }
        }
#pragma unroll
        for (int q = 0; q < NQ; ++q) ang[q] = wave_sum(acc[q]) + bin[q];
    }

    // ---- layer 0 on |0..0>: product state built directly ----
    // fused F_q = Rot(l0,q) * RX(ang_q); only its first column (f0,f1) matters
    f2 f0[NQ], f1[NQ];
    {
        const float4* g4 = (const float4*)gates;       // uniform -> s_load
#pragma unroll
        for (int q = 0; q < NQ; ++q) {
            const float4 p0 = g4[q * 2];
            const float4 p1 = g4[q * 2 + 1];
            float s, c;
            __sincosf(0.5f * ang[q], &s, &c);
            f2 a, b;
            a.x = p0.x * c + s * p0.w;  a.y = p0.y * c - s * p0.z;
            b.x = p1.x * c + s * p1.w;  b.y = p1.y * c - s * p1.z;
            f0[q] = a; f1[q] = b;
        }
    }
    // lane-bit factors: bit b (0..5) <-> wire 9-b
    f2 s0 = ((lane >> 0) & 1) ? f1[9] : f0[9];
    f2 s1 = ((lane >> 1) & 1) ? f1[8] : f0[8];
    f2 s2 = ((lane >> 2) & 1) ? f1[7] : f0[7];
    f2 s3 = ((lane >> 3) & 1) ? f1[6] : f0[6];
    f2 s4 = ((lane >> 4) & 1) ? f1[5] : f0[5];
    f2 s5 = ((lane >> 5) & 1) ? f1[4] : f0[4];
    const f2 L = cmul(cmul(cmul(s0, s1), cmul(s2, s3)), cmul(s4, s5));

    f2 LT[4], U2[4];
#pragma unroll
    for (int j = 0; j < 4; ++j) {
        // reg bits 0,1 <-> index bits 6,7 <-> wires 3,2
        const f2 t = cmul((j & 1) ? f1[3] : f0[3], (j & 2) ? f1[2] : f0[2]);
        LT[j] = cmul(L, t);
        // reg bits 2,3 <-> index bits 8,9 <-> wires 1,0
        U2[j] = cmul((j & 1) ? f1[1] : f0[1], (j & 2) ? f1[0] : f0[0]);
    }
    f2 v[NREG];
#pragma unroll
    for (int r = 0; r < NREG; ++r) v[r] = cmul(LT[r & 3], U2[r >> 2]);

    // ---- remaining circuit ----
    cnot_ring<0>(v, lane);
    rot_layer<1>(v, lane, gates);  cnot_ring<1>(v, lane);
    rot_layer<2>(v, lane, gates);  cnot_ring<2>(v, lane);

    // ---- expectation values <Z_w>, wire w <-> bit 9-w ----
    float pr[NREG];
#pragma unroll
    for (int r = 0; r < NREG; ++r) pr[r] = v[r].x * v[r].x + v[r].y * v[r].y;

    float sumAll = 0.f;
#pragma unroll
    for (int r = 0; r < NREG; ++r) sumAll += pr[r];

    float sgn[4];
#pragma unroll
    for (int rb = 0; rb < 4; ++rb) {
        float s = 0.f;
#pragma unroll
        for (int r = 0; r < NREG; ++r) s += ((r >> rb) & 1) ? -pr[r] : pr[r];
        sgn[rb] = s;
    }

    float ev[NQ];
#pragma unroll
    for (int w = 0; w < NQ; ++w) {
        const int b = 9 - w;
        const float val = (b >= 6) ? sgn[b - 6]
                                   : (((lane >> b) & 1) ? -sumAll : sumAll);
        ev[w] = wave_sum(val);
    }

    // ---- out[samp] = ev @ Wout + bout ----
#pragma unroll
    for (int j = 0; j < CDIM / 64; ++j) {
        const int d = lane + j * 64;
        float o = bout[d];
#pragma unroll
        for (int q = 0; q < NQ; ++q) o += ev[q] * Wout[q * CDIM + d];
        out[(size_t)samp * CDIM + d] = o;
    }
}

extern "C" void kernel_launch(void* const* d_in, const int* in_sizes, int n_in,
                              void* d_out, int out_size, void* d_ws, size_t ws_size,
                              hipStream_t stream) {
    const float* z    = (const float*)d_in[0];
    const float* Win  = (const float*)d_in[1];
    const float* bin  = (const float*)d_in[2];
    const float* wts  = (const float*)d_in[3];
    const float* Wout = (const float*)d_in[4];
    const float* bout = (const float*)d_in[5];
    float* outp       = (float*)d_out;
    float* gates      = (float*)d_ws;       // 30 gates * 8 floats = 960 B

    prep_gates<<<1, 64, 0, stream>>>(wts, gates);

    const int batch  = in_sizes[0] / CDIM;   // 2048
    const int blocks = batch / WPB;          // 512
    qembed<<<blocks, 64 * WPB, 0, stream>>>(z, Win, bin, gates, Wout, bout, outp);
}